// Round 8
// baseline (426.614 us; speedup 1.0000x reference)
//
#include <hip/hip_runtime.h>
#include <hip/hip_bf16.h>
#include <math.h>

#define WORDC 30000
#define F_TOT 80000
#define NTOK  2048
#define DMODEL 256
#define FFDIM 512
#define NHEAD 8
#define HDIM  32
#define SEQL  64
#define NBLK  256

typedef __attribute__((ext_vector_type(8))) short bf16x8;
typedef __attribute__((ext_vector_type(8))) unsigned short u16x8;
typedef __attribute__((ext_vector_type(4))) float f32x4;

__device__ __forceinline__ unsigned short f32_to_bf16_rne(float x) {
    unsigned int u = __float_as_uint(x);
    unsigned int r = (u + 0x7FFFu + ((u >> 16) & 1u)) >> 16;
    return (unsigned short)r;
}

__device__ __forceinline__ u16x8 cvt8(float4 a, float4 b) {
    u16x8 v;
    v[0] = f32_to_bf16_rne(a.x); v[1] = f32_to_bf16_rne(a.y);
    v[2] = f32_to_bf16_rne(a.z); v[3] = f32_to_bf16_rne(a.w);
    v[4] = f32_to_bf16_rne(b.x); v[5] = f32_to_bf16_rne(b.y);
    v[6] = f32_to_bf16_rne(b.z); v[7] = f32_to_bf16_rne(b.w);
    return v;
}

// device-scope grid barrier: monotone counter, all NBLK blocks co-resident
__device__ __forceinline__ void gbar(unsigned* cnt, unsigned target) {
    __syncthreads();
    __threadfence();
    if (threadIdx.x == 0) {
        atomicAdd(cnt, 1u);
        while (atomicAdd(cnt, 0u) < target) __builtin_amdgcn_s_sleep(2);
        __threadfence();
    }
    __syncthreads();
}

// ---------------------------------------------------------------------------
// Build bitmap of used features, one block.
// ---------------------------------------------------------------------------
__global__ __launch_bounds__(256) void mark_feats(
    const int* __restrict__ word_idx,
    const int* __restrict__ ngram_idx,
    unsigned int* __restrict__ bm)
{
    __shared__ unsigned int lbm[2500];
    const int tid = threadIdx.x;
    for (int i = tid; i < 2500; i += 256) lbm[i] = 0u;
    __syncthreads();
    for (int j = tid; j < NTOK; j += 256) {
        int f = word_idx[j];
        atomicOr(&lbm[f >> 5], 1u << (f & 31));
    }
    for (int j = tid; j < NTOK * 6; j += 256) {
        int f = WORDC + ngram_idx[j];
        atomicOr(&lbm[f >> 5], 1u << (f & 31));
    }
    __syncthreads();
    for (int i = tid; i < 2500; i += 256) bm[i] = lbm[i];
}

// ---------------------------------------------------------------------------
// Transpose fc1_w (store-pruned) + cvt transformer weights.
// ---------------------------------------------------------------------------
__global__ __launch_bounds__(256) void transpose_cvt(
    const float* __restrict__ fc1_w,
    unsigned short* __restrict__ fc1T,
    const unsigned int* __restrict__ bm,
    const float* __restrict__ s0, const float* __restrict__ s1,
    const float* __restrict__ s2, const float* __restrict__ s3,
    unsigned short* __restrict__ d0, unsigned short* __restrict__ d1,
    unsigned short* __restrict__ d2, unsigned short* __restrict__ d3)
{
    __shared__ float tile[64][65];
    const int bid = blockIdx.x;
    const int tid = threadIdx.x;

    if (bid < 10000) {
        const int f0 = (bid % 1250) * 64;
        const int j0 = (bid / 1250) * 64;

        const int fr = (tid & 15) * 4;
        const int jr = tid >> 4;
        #pragma unroll
        for (int p = 0; p < 4; ++p) {
            int j = j0 + p * 16 + jr;
            float4 v = *(const float4*)&fc1_w[(long)j * F_TOT + f0 + fr];
            tile[fr + 0][p * 16 + jr] = v.x;
            tile[fr + 1][p * 16 + jr] = v.y;
            tile[fr + 2][p * 16 + jr] = v.z;
            tile[fr + 3][p * 16 + jr] = v.w;
        }
        __syncthreads();

        const int jc  = (tid & 15) * 4;
        const int fr2 = tid >> 4;
        #pragma unroll
        for (int p = 0; p < 4; ++p) {
            int fi = p * 16 + fr2;
            int f  = f0 + fi;
            if ((bm[f >> 5] >> (f & 31)) & 1u) {
                ushort4 o;
                o.x = f32_to_bf16_rne(tile[fi][jc + 0]);
                o.y = f32_to_bf16_rne(tile[fi][jc + 1]);
                o.z = f32_to_bf16_rne(tile[fi][jc + 2]);
                o.w = f32_to_bf16_rne(tile[fi][jc + 3]);
                *(ushort4*)&fc1T[(long)f * FFDIM + j0 + jc] = o;
            }
        }
    } else {
        int s = bid - 10000;
        int ten = s / 48, b48 = s % 48;
        const float* src; unsigned short* dst; int n4;
        switch (ten) {
            case 0:  src = s0; dst = d0; n4 = 2 * 768 * 256 / 4;  break;
            case 1:  src = s1; dst = d1; n4 = 2 * 256 * 256 / 4;  break;
            case 2:  src = s2; dst = d2; n4 = 2 * 1024 * 256 / 4; break;
            default: src = s3; dst = d3; n4 = 2 * 256 * 1024 / 4; break;
        }
        for (int i = b48 * 256 + tid; i < n4; i += 48 * 256) {
            float4 v = ((const float4*)src)[i];
            ushort4 o;
            o.x = f32_to_bf16_rne(v.x);
            o.y = f32_to_bf16_rne(v.y);
            o.z = f32_to_bf16_rne(v.z);
            o.w = f32_to_bf16_rne(v.w);
            ((ushort4*)dst)[i] = o;
        }
    }
}

// ===========================================================================
// MEGAKERNEL: embed + 2 transformer layers, grid 256 x 512, 1 block/CU,
// device-scope grid barriers between phases.
// ===========================================================================
// LDS overlay offsets (bytes), total 114176:
//  embed: feats@0(256) nf@256(32) x1f@512(16384) pf@16896(8192)
//  attn : sA@0(33792) sWp@33792(55296) sQ@89088(5120) sK@94208(5120)
//         sVt@99328(4608) sP@103936(9216) sfmx@113152(512) sfsm@113664(512)
//  outln: sA@0(8448) sWp@8448(36864) redS@45312(256) redQ@45568(256)
//  ffn  : sX@0(8448) x1s@8448(33024) sWp@41472(36864) redS@78336(256) redQ@78592(256)

__global__ __launch_bounds__(512, 2) void mega_kernel(
    const int* __restrict__ word_idx,
    const int* __restrict__ ngram_idx,
    const unsigned short* __restrict__ fc1T,
    const float* __restrict__ fc1_b,
    const float* __restrict__ fc2_w,
    const float* __restrict__ fc2_b,
    const unsigned short* __restrict__ qkvT,
    const float* __restrict__ qkv_b,
    const unsigned short* __restrict__ outT,
    const float* __restrict__ out_b,
    const float* __restrict__ ln1_g, const float* __restrict__ ln1_bt,
    const unsigned short* __restrict__ ff1T,
    const float* __restrict__ ff1_b,
    const unsigned short* __restrict__ ff2T,
    const float* __restrict__ ff2_b,
    const float* __restrict__ ln2_g, const float* __restrict__ ln2_bt,
    float* __restrict__ x,
    float* __restrict__ attn_raw,
    unsigned* __restrict__ bar)
{
    __shared__ __align__(16) char smem[114176];
    const int bid  = blockIdx.x;
    const int tid  = threadIdx.x;
    const int lane = tid & 63;
    const int w    = tid >> 6;
    const int fr   = lane & 15;
    const int ksub = lane >> 4;
    unsigned target = NBLK;

    // ================= phase 0: embed =================
    {
        int*   feats = (int*)(smem + 0);       // [8][8]
        int*   nf    = (int*)(smem + 256);
        float* x1f   = (float*)(smem + 512);   // [8][512]
        float* pf    = (float*)(smem + 16896); // [8][256]
        const int t0 = bid * 8;

        if (tid < 8) {
            int t = t0 + tid;
            int cnt = 0;
            feats[tid * 8 + cnt++] = word_idx[t];
            for (int k = 0; k < 6; ++k) {
                int f = WORDC + ngram_idx[t * 6 + k];
                bool dup = false;
                for (int s = 1; s < cnt; ++s)
                    if (feats[tid * 8 + s] == f) dup = true;
                if (!dup) feats[tid * 8 + cnt++] = f;
            }
            nf[tid] = cnt;
        }
        __syncthreads();

        // x1: thread = column j (0..511), 8 tokens
        {
            float bb = fc1_b[tid];
            #pragma unroll
            for (int tt = 0; tt < 8; ++tt) {
                float a0 = bb;
                int n = nf[tt];
                for (int s = 0; s < n; ++s) {
                    unsigned short v = fc1T[(long)feats[tt * 8 + s] * FFDIM + tid];
                    a0 += __uint_as_float((unsigned)v << 16);
                }
                x1f[tt * 512 + tid] = fmaxf(a0, 0.f);
            }
        }
        __syncthreads();

        // fc2: thread = (d, k-half)
        {
            int d = tid & 255, kh = tid >> 8;
            float acc[8];
            float cb = (kh == 0) ? fc2_b[d] : 0.f;
            #pragma unroll
            for (int tt = 0; tt < 8; ++tt) acc[tt] = cb;
            const float* wrow = fc2_w + d * FFDIM + kh * 256;
            const float* xbase = x1f + kh * 256;
            for (int k = 0; k < 256; ++k) {
                float wv = wrow[k];
                #pragma unroll
                for (int tt = 0; tt < 8; ++tt) acc[tt] += wv * xbase[tt * 512 + k];
            }
            if (kh == 1) {
                #pragma unroll
                for (int tt = 0; tt < 8; ++tt) pf[tt * 256 + d] = acc[tt];
            }
            __syncthreads();
            if (kh == 0) {
                #pragma unroll
                for (int tt = 0; tt < 8; ++tt)
                    x[(long)(t0 + tt) * DMODEL + d] = acc[tt] + pf[tt * 256 + d];
            }
        }
    }
    gbar(bar, target); target += NBLK;

    for (int li = 0; li < 2; ++li) {
        // ================= attn: block = (b,h) =================
        {
            unsigned short* sA  = (unsigned short*)(smem + 0);      // [64][264]
            unsigned short* sWp = (unsigned short*)(smem + 33792);  // [8][48*72]
            unsigned short* sQ  = (unsigned short*)(smem + 89088);  // [64][40]
            unsigned short* sK  = (unsigned short*)(smem + 94208);  // [64][40]
            unsigned short* sVt = (unsigned short*)(smem + 99328);  // [32][72]
            unsigned short* sP  = (unsigned short*)(smem + 103936); // [64][72]
            float* sfmx = (float*)(smem + 113152);                  // [2][64]
            float* sfsm = (float*)(smem + 113664);                  // [2][64]

            const unsigned short* Wq = qkvT + (long)li * 768 * 256;
            const float* bq = qkv_b + li * 768;
            const int b = bid >> 3;
            const int h = bid & 7;
            const int rg = w & 3;
            const int ch = w >> 2;
            const int row0 = b * SEQL;

            #pragma unroll
            for (int j = 0; j < 4; ++j) {
                int c = j * 512 + tid;
                int row = c >> 5, c8 = c & 31;
                const float* ap = &x[(long)(row0 + row) * DMODEL + c8 * 8];
                float4 a0 = *(const float4*)ap;
                float4 a1 = *(const float4*)(ap + 4);
                *(u16x8*)&sA[row * 264 + c8 * 8] = cvt8(a0, a1);
            }

            int lr6[6], grow6[6];
            const int wcc = (lane & 7) * 8;
            #pragma unroll
            for (int j = 0; j < 6; ++j) {
                int lr = j * 8 + (lane >> 3);
                lr6[j] = lr;
                int c = ch * 48 + lr;
                grow6[j] = (c >> 5) * 256 + h * HDIM + (c & 31);
            }
            u16x8 wc[6], wn[6];
            #pragma unroll
            for (int j = 0; j < 6; ++j)
                wc[j] = *(const u16x8*)&Wq[(long)grow6[j] * DMODEL + wcc];

            __syncthreads();

            f32x4 acc[3] = {};
            for (int t = 0; t < 4; ++t) {
                #pragma unroll
                for (int j = 0; j < 6; ++j)
                    *(u16x8*)&sWp[w * 3456 + lr6[j] * 72 + wcc] = wc[j];
                if (t < 3) {
                    int k0 = (t + 1) * 64;
                    #pragma unroll
                    for (int j = 0; j < 6; ++j)
                        wn[j] = *(const u16x8*)&Wq[(long)grow6[j] * DMODEL + k0 + wcc];
                }
                #pragma unroll
                for (int kk = 0; kk < 2; ++kk) {
                    bf16x8 af = *(bf16x8*)&sA[(rg * 16 + fr) * 264 + t * 64 + kk * 32 + ksub * 8];
                    #pragma unroll
                    for (int ni = 0; ni < 3; ++ni) {
                        bf16x8 bf = *(bf16x8*)&sWp[w * 3456 + (ni * 16 + fr) * 72 + kk * 32 + ksub * 8];
                        acc[ni] = __builtin_amdgcn_mfma_f32_16x16x32_bf16(af, bf, acc[ni], 0, 0, 0);
                    }
                }
                if (t < 3) {
                    #pragma unroll
                    for (int j = 0; j < 6; ++j) wc[j] = wn[j];
                }
            }

            const float scale = 0.17677669529663687f;
            #pragma unroll
            for (int ni = 0; ni < 3; ++ni) {
                int c = ch * 48 + ni * 16 + fr;
                int part = c >> 5, pc = c & 31;
                float bv = bq[part * 256 + h * HDIM + pc];
                #pragma unroll
                for (int r = 0; r < 4; ++r) {
                    int row = rg * 16 + ksub * 4 + r;
                    float v = acc[ni][r] + bv;
                    if (part == 0)      sQ[row * 40 + pc] = f32_to_bf16_rne(v * scale);
                    else if (part == 1) sK[row * 40 + pc] = f32_to_bf16_rne(v);
                    else                sVt[pc * 72 + row] = f32_to_bf16_rne(v);
                }
            }
            __syncthreads();

            f32x4 s4[2];
            {
                bf16x8 afq = *(bf16x8*)&sQ[(rg * 16 + fr) * 40 + ksub * 8];
                #pragma unroll
                for (int ni = 0; ni < 2; ++ni) {
                    bf16x8 bfk = *(bf16x8*)&sK[(ch * 32 + ni * 16 + fr) * 40 + ksub * 8];
                    f32x4 z = {};
                    s4[ni] = __builtin_amdgcn_mfma_f32_16x16x32_bf16(afq, bfk, z, 0, 0, 0);
                }
            }

            #pragma unroll
            for (int r = 0; r < 4; ++r) {
                float m = fmaxf(s4[0][r], s4[1][r]);
                m = fmaxf(m, __shfl_xor(m, 1));
                m = fmaxf(m, __shfl_xor(m, 2));
                m = fmaxf(m, __shfl_xor(m, 4));
                m = fmaxf(m, __shfl_xor(m, 8));
                if (fr == 0) sfmx[ch * 64 + rg * 16 + ksub * 4 + r] = m;
            }
            __syncthreads();
            float minv[4];
            #pragma unroll
            for (int r = 0; r < 4; ++r) {
                int row = rg * 16 + ksub * 4 + r;
                float m = fmaxf(sfmx[row], sfmx[64 + row]);
                float p0 = __expf(s4[0][r] - m);
                float p1 = __expf(s4[1][r] - m);
                sP[row * 72 + ch * 32 + fr]      = f32_to_bf16_rne(p0);
                sP[row * 72 + ch * 32 + 16 + fr] = f32_to_bf16_rne(p1);
                float s = p0 + p1;
                s += __shfl_xor(s, 1);
                s += __shfl_xor(s, 2);
                s += __shfl_xor(s, 4);
                s += __shfl_xor(s, 8);
                if (fr == 0) sfsm[ch * 64 + row] = s;
            }
            __syncthreads();
            #pragma unroll
            for (int r = 0; r < 4; ++r) {
                int row = rg * 16 + ksub * 4 + r;
                minv[r] = 1.f / (sfsm[row] + sfsm[64 + row]);
            }

            f32x4 o4 = {};
            #pragma unroll
            for (int kc = 0; kc < 2; ++kc) {
                bf16x8 afp = *(bf16x8*)&sP[(rg * 16 + fr) * 72 + kc * 32 + ksub * 8];
                bf16x8 bfv = *(bf16x8*)&sVt[(ch * 16 + fr) * 72 + kc * 32 + ksub * 8];
                o4 = __builtin_amdgcn_mfma_f32_16x16x32_bf16(afp, bfv, o4, 0, 0, 0);
            }
            #pragma unroll
            for (int r = 0; r < 4; ++r) {
                int row = row0 + rg * 16 + ksub * 4 + r;
                attn_raw[(long)row * DMODEL + h * HDIM + ch * 16 + fr] = o4[r] * minv[r];
            }
        }
        gbar(bar, target); target += NBLK;

        // ================= out-proj + LN: block = 8 rows =================
        {
            unsigned short* sA  = (unsigned short*)(smem + 0);     // [16][264]
            unsigned short* sWp = (unsigned short*)(smem + 8448);  // [8][32*72]
            float* redS = (float*)(smem + 45312);                  // [8][8]
            float* redQ = (float*)(smem + 45568);

            const unsigned short* Wb = outT + (long)li * 256 * 256;
            const float* bias = out_b + li * 256;
            const float* g    = ln1_g + li * 256;
            const float* beta = ln1_bt + li * 256;
            const int m0 = bid * 8;

            {
                int row = tid >> 5, c8 = tid & 31;
                if (tid < 256) {
                    const float* ap = &attn_raw[(long)(m0 + row) * DMODEL + c8 * 8];
                    float4 a0 = *(const float4*)ap;
                    float4 a1 = *(const float4*)(ap + 4);
                    *(u16x8*)&sA[row * 264 + c8 * 8] = cvt8(a0, a1);
                } else {
                    u16x8 z = {};
                    *(u16x8*)&sA[row * 264 + c8 * 8] = z;
                }
            }

            const int lrb = lane >> 3;
            const int wcc = (lane & 7) * 8;
            u16x8 wc[4], wn[4];
            #pragma unroll
            for (int j = 0; j < 4; ++j)
                wc[j] = *(const u16x8*)&Wb[(long)(w * 32 + j * 8 + lrb) * DMODEL + wcc];

            __syncthreads();

            f32x4 acc[2] = {};
            for (int t = 0; t < 4; ++t) {
                #pragma unroll
                for (int j = 0; j < 4; ++j)
                    *(u16x8*)&sWp[w * 2304 + (j * 8 + lrb) * 72 + wcc] = wc[j];
                if (t < 3) {
                    int k0 = (t + 1) * 64;
                    #pragma unroll
                    for (int j = 0; j < 4; ++j)
                        wn[j] = *(const u16x8*)&Wb[(long)(w * 32 + j * 8 + lrb) * DMODEL + k0 + wcc];
                }
                #pragma unroll
                for (int kk = 0; kk < 2; ++kk) {
                    bf16x8 af = *(bf16x8*)&sA[fr * 264 + t * 64 + kk * 32 + ksub * 8];
                    #pragma unroll
                    for (int ni = 0; ni < 2; ++ni) {
                        bf16x8 bf = *(bf16x8*)&sWp[w * 2304 + (ni * 16 + fr) * 72 + kk * 32 + ksub * 8];
                        acc[ni] = __builtin_amdgcn_mfma_f32_16x16x32_bf16(af, bf, acc[ni], 0, 0, 0);
                    }
                }
                if (t < 3) {
                    #pragma unroll
                    for (int j = 0; j < 4; ++j) wc[j] = wn[j];
                }
            }

            float vres[2][4];
            #pragma unroll
            for (int ni = 0; ni < 2; ++ni) {
                int col = w * 32 + ni * 16 + fr;
                float bv = bias[col];
                #pragma unroll
                for (int r = 0; r < 4; ++r) {
                    int rl = ksub * 4 + r;
                    vres[ni][r] = (rl < 8)
                        ? acc[ni][r] + bv + x[(long)(m0 + rl) * DMODEL + col]
                        : 0.f;
                }
            }

            #pragma unroll
            for (int r = 0; r < 4; ++r) {
                float s  = vres[0][r] + vres[1][r];
                float qq = vres[0][r] * vres[0][r] + vres[1][r] * vres[1][r];
                #pragma unroll
                for (int mask = 1; mask < 16; mask <<= 1) {
                    s  += __shfl_xor(s, mask);
                    qq += __shfl_xor(qq, mask);
                }
                if (fr == 0 && ksub < 2) {
                    redS[w * 8 + ksub * 4 + r] = s;
                    redQ[w * 8 + ksub * 4 + r] = qq;
                }
            }
            __syncthreads();

            #pragma unroll
            for (int r = 0; r < 4; ++r) {
                int rl = ksub * 4 + r;
                if (rl < 8) {
                    float sum = 0.f, sumq = 0.f;
                    #pragma unroll
                    for (int ww = 0; ww < 8; ++ww) {
                        sum  += redS[ww * 8 + rl];
                        sumq += redQ[ww * 8 + rl];
                    }
                    float mean = sum * (1.f / 256.f);
                    float var  = sumq * (1.f / 256.f) - mean * mean;
                    float rstd = rsqrtf(var + 1e-5f);
                    #pragma unroll
                    for (int ni = 0; ni < 2; ++ni) {
                        int col = w * 32 + ni * 16 + fr;
                        x[(long)(m0 + rl) * DMODEL + col] =
                            (vres[ni][r] - mean) * rstd * g[col] + beta[col];
                    }
                }
            }
        }
        gbar(bar, target); target += NBLK;

        // ================= FFN: block = 8 rows =================
        {
            unsigned short* sX  = (unsigned short*)(smem + 0);      // [16][264]
            unsigned short* x1s = (unsigned short*)(smem + 8448);   // [16][1032]
            unsigned short* sWp = (unsigned short*)(smem + 41472);  // [8][32*72]
            float* redS = (float*)(smem + 78336);                   // [8][8]
            float* redQ = (float*)(smem + 78592);

            const unsigned short* W1 = ff1T + (long)li * 1024 * 256;
            const float* b1 = ff1_b + li * 1024;
            const unsigned short* W2 = ff2T + (long)li * 256 * 1024;
            const float* b2 = ff2_b + li * 256;
            const float* g    = ln2_g + li * 256;
            const float* beta = ln2_bt + li * 256;
            const int m0 = bid * 8;

            {
                int row = tid >> 5, c8 = tid & 31;
                if (tid < 256) {
                    const float* xp = &x[(long)(m0 + row) * DMODEL + c8 * 8];
                    float4 a0 = *(const float4*)xp;
                    float4 a1 = *(const float4*)(xp + 4);
                    *(u16x8*)&sX[row * 264 + c8 * 8] = cvt8(a0, a1);
                } else {
                    u16x8 z = {};
                    *(u16x8*)&sX[row * 264 + c8 * 8] = z;
                }
            }

            const int lrb = lane >> 3;
            const int wcc = (lane & 7) * 8;
            u16x8 wc[4], wn[4];
            #pragma unroll
            for (int j = 0; j < 4; ++j)
                wc[j] = *(const u16x8*)&W1[(long)(w * 32 + j * 8 + lrb) * DMODEL + wcc];

            __syncthreads();

            f32x4 acc[2] = {};
            for (int t = 0; t < 32; ++t) {
                #pragma unroll
                for (int j = 0; j < 4; ++j)
                    *(u16x8*)&sWp[w * 2304 + (j * 8 + lrb) * 72 + wcc] = wc[j];
                if (t < 31) {
                    int tn = t + 1;
                    if (tn < 16) {
                        int nc = tn >> 2, kq = tn & 3;
                        #pragma unroll
                        for (int j = 0; j < 4; ++j)
                            wn[j] = *(const u16x8*)&W1[(long)(nc * 256 + w * 32 + j * 8 + lrb) * DMODEL
                                                       + kq * 64 + wcc];
                    } else {
                        int t2 = tn - 16;
                        #pragma unroll
                        for (int j = 0; j < 4; ++j)
                            wn[j] = *(const u16x8*)&W2[(long)(w * 32 + j * 8 + lrb) * 1024
                                                       + t2 * 64 + wcc];
                    }
                }
                #pragma unroll
                for (int kk = 0; kk < 2; ++kk) {
                    bf16x8 af;
                    if (t < 16)
                        af = *(bf16x8*)&sX[fr * 264 + (t & 3) * 64 + kk * 32 + ksub * 8];
                    else
                        af = *(bf16x8*)&x1s[fr * 1032 + (t - 16) * 64 + kk * 32 + ksub * 8];
                    #pragma unroll
                    for (int ni = 0; ni < 2; ++ni) {
                        bf16x8 bf = *(bf16x8*)&sWp[w * 2304 + (ni * 16 + fr) * 72 + kk * 32 + ksub * 8];
                        acc[ni] = __builtin_amdgcn_mfma_f32_16x16x32_bf16(af, bf, acc[ni], 0, 0, 0);
                    }
                }
                if (t < 16 && (t & 3) == 3) {
                    int nc = t >> 2;
                    #pragma unroll
                    for (int ni = 0; ni < 2; ++ni) {
                        int col = nc * 256 + w * 32 + ni * 16 + fr;
                        float bv = b1[col];
                        #pragma unroll
                        for (int r = 0; r < 4; ++r) {
                            int rl = ksub * 4 + r;
                            x1s[rl * 1032 + col] = (rl < 8)
                                ? f32_to_bf16_rne(fmaxf(acc[ni][r] + bv, 0.f))
                                : (unsigned short)0;
                        }
                        acc[ni] = (f32x4){};
                    }
                }
                if (t == 15) __syncthreads();
                if (t < 31) {
                    #pragma unroll
                    for (int j = 0; j < 4; ++j) wc[j] = wn[j];
                }
            }

            float vres[2][4];
            #pragma unroll
            for (int ni = 0; ni < 2; ++ni) {
                int col = w * 32 + ni * 16 + fr;
                float bv = b2[col];
                #pragma unroll
                for (int r = 0; r < 4; ++r) {
                    int rl = ksub * 4 + r;
                    vres[ni][r] = (rl < 8)
                        ? acc[ni][r] + bv + x[(long)(m0 + rl) * DMODEL + col]
                        : 0.f;
                }
            }

            #pragma unroll
            for (int r = 0; r < 4; ++r) {
                float s  = vres[0][r] + vres[1][r];
                float qq = vres[0][r] * vres[0][r] + vres[1][r] * vres[1][r];
                #pragma unroll
                for (int mask = 1; mask < 16; mask <<= 1) {
                    s  += __shfl_xor(s, mask);
                    qq += __shfl_xor(qq, mask);
                }
                if (fr == 0 && ksub < 2) {
                    redS[w * 8 + ksub * 4 + r] = s;
                    redQ[w * 8 + ksub * 4 + r] = qq;
                }
            }
            __syncthreads();

            #pragma unroll
            for (int r = 0; r < 4; ++r) {
                int rl = ksub * 4 + r;
                if (rl < 8) {
                    float sum = 0.f, sumq = 0.f;
                    #pragma unroll
                    for (int ww = 0; ww < 8; ++ww) {
                        sum  += redS[ww * 8 + rl];
                        sumq += redQ[ww * 8 + rl];
                    }
                    float mean = sum * (1.f / 256.f);
                    float var  = sumq * (1.f / 256.f) - mean * mean;
                    float rstd = rsqrtf(var + 1e-5f);
                    #pragma unroll
                    for (int ni = 0; ni < 2; ++ni) {
                        int col = w * 32 + ni * 16 + fr;
                        x[(long)(m0 + rl) * DMODEL + col] =
                            (vres[ni][r] - mean) * rstd * g[col] + beta[col];
                    }
                }
            }
        }
        if (li == 0) { gbar(bar, target); target += NBLK; }
    }
}

// ===========================================================================
// Fallback (fp32) path kernels — used only if ws is too small.
// ===========================================================================
__global__ __launch_bounds__(256) void embed_kernel(
    const int* __restrict__ word_idx,
    const int* __restrict__ ngram_idx,
    const float* __restrict__ fc1_w,
    const float* __restrict__ fc1_b,
    const float* __restrict__ fc2_w,
    const float* __restrict__ fc2_b,
    float* __restrict__ x)
{
    __shared__ int   feats[8][8];
    __shared__ int   nf[8];
    __shared__ float x1[8][FFDIM];

    const int t0  = blockIdx.x * 8;
    const int tid = threadIdx.x;

    if (tid < 8) {
        int t = t0 + tid;
        int cnt = 0;
        feats[tid][cnt++] = word_idx[t];
        for (int k = 0; k < 6; ++k) {
            int f = WORDC + ngram_idx[t * 6 + k];
            bool dup = false;
            for (int s = 1; s < cnt; ++s)
                if (feats[tid][s] == f) dup = true;
            if (!dup) feats[tid][cnt++] = f;
        }
        nf[tid] = cnt;
    }
    __syncthreads();

    for (int it = 0; it < 16; ++it) {
        int item = it * 256 + tid;
        int tt = item >> 9;
        int j  = item & 511;
        float acc = fc1_b[j];
        int n = nf[tt];
        const float* rowbase = fc1_w + (long)j * F_TOT;
        for (int s = 0; s < n; ++s)
            acc += rowbase[feats[tt][s]];
        x1[tt][j] = fmaxf(acc, 0.f);
    }
    __syncthreads();

    const int d = tid;
    float acc[8];
    float bb = fc2_b[d];
    #pragma unroll
    for (int tt = 0; tt < 8; ++tt) acc[tt] = bb;
    const float* wrow = fc2_w + d * FFDIM;
    for (int k = 0; k < FFDIM; ++k) {
        float wv = wrow[k];
        #pragma unroll
        for (int tt = 0; tt < 8; ++tt) acc[tt] += wv * x1[tt][k];
    }
    #pragma unroll
    for (int tt = 0; tt < 8; ++tt)
        x[(t0 + tt) * DMODEL + d] = acc[tt];
}

template<bool RELU>
__global__ __launch_bounds__(256) void gemm_bias(
    const float* __restrict__ A,
    const float* __restrict__ W,
    const float* __restrict__ bias,
    float* __restrict__ C,
    int M, int N, int K)
{
    __shared__ float sA[16][64];
    __shared__ float sW[16][64];

    const int tid = threadIdx.x;
    const int tx = tid & 15;
    const int ty = tid >> 4;
    const int m0 = blockIdx.y * 64;
    const int n0 = blockIdx.x * 64;

    const int lr = tid >> 2;
    const int lc = tid & 3;

    float acc[4][4] = {};

    for (int k0 = 0; k0 < K; k0 += 16) {
        float4 av = *(const float4*)&A[(long)(m0 + lr) * K + k0 + lc * 4];
        float4 wv = *(const float4*)&W[(long)(n0 + lr) * K + k0 + lc * 4];
        __syncthreads();
        sA[lc * 4 + 0][lr] = av.x; sA[lc * 4 + 1][lr] = av.y;
        sA[lc * 4 + 2][lr] = av.z; sA[lc * 4 + 3][lr] = av.w;
        sW[lc * 4 + 0][lr] = wv.x; sW[lc * 4 + 1][lr] = wv.y;
        sW[lc * 4 + 2][lr] = wv.z; sW[lc * 4 + 3][lr] = wv.w;
        __syncthreads();
        #pragma unroll
        for (int k = 0; k < 16; ++k) {
            float4 a4 = *(const float4*)&sA[k][ty * 4];
            float4 b4 = *(const float4*)&sW[k][tx * 4];
            float am[4] = {a4.x, a4.y, a4.z, a4.w};
            float bn[4] = {b4.x, b4.y, b4.z, b4.w};
            #pragma unroll
            for (int i = 0; i < 4; ++i)
                #pragma unroll
                for (int j = 0; j < 4; ++j)
                    acc[i][j] += am[i] * bn[j];
        }
    }

    float4 bv = *(const float4*)&bias[n0 + tx * 4];
    #pragma unroll
    for (int i = 0; i < 4; ++i) {
        int m = m0 + ty * 4 + i;
        float4 o;
        o.x = acc[i][0] + bv.x;
        o.y = acc[i][1] + bv.y;
        o.z = acc[i][2] + bv.z;
        o.w = acc[i][3] + bv.w;
        if (RELU) {
            o.x = fmaxf(o.x, 0.f); o.y = fmaxf(o.y, 0.f);
            o.z = fmaxf(o.z, 0.f); o.w = fmaxf(o.w, 0.f);
        }
        *(float4*)&C[(long)m * N + n0 + tx * 4] = o;
    }
}

__global__ __launch_bounds__(256) void attn_kernel(
    const float* __restrict__ qkv,
    float* __restrict__ o)
{
    const int b = blockIdx.x >> 3;
    const int h = blockIdx.x & 7;
    const int tid = threadIdx.x;
    const int q = tid >> 2;
    const int p = tid & 3;

    __shared__ float Kt[SEQL][HDIM + 1];
    __shared__ float Vt[SEQL][HDIM + 1];
    __shared__ float S[SEQL][SEQL + 1];

    const float scale = 0.17677669529663687f;

    {
        int fidx = tid * 2;
        int row  = fidx >> 3;
        int c    = (fidx & 7) * 4;
        const float* kb = qkv + (long)(b * SEQL + row) * 768 + 256 + h * HDIM + c;
        float4 k0 = *(const float4*)kb;
        float4 k1 = *(const float4*)(kb + 4);
        float4 v0 = *(const float4*)(kb + 256);
        float4 v1 = *(const float4*)(kb + 260);
        *(float4*)&Kt[row][c]     = k0;
        *(float4*)&Kt[row][c + 4] = k1;
        *(float4*)&Vt[row][c]     = v0;
        *(float4*)&Vt[row][c + 4] = v1;
    }

    float qreg[HDIM];
    {
        const float* qb = qkv + (long)(b * SEQL + q) * 768 + h * HDIM;
        #pragma unroll
        for (int c = 0; c < HDIM / 4; ++c) {
            float4 v = *(const float4*)(qb + c * 4);
            qreg[c * 4 + 0] = v.x * scale;
            qreg[c * 4 + 1] = v.y * scale;
            qreg[c * 4 + 2] = v.z * scale;
            qreg[c * 4 + 3] = v.w * scale;
        }
    }
    __syncthreads();

    float sc[16];
    float mx = -1e30f;
    #pragma unroll
    for (int i = 0; i < 16; ++i) {
        int jj = p * 16 + i;
        float s = 0.f;
        #pragma unroll
        for (int d = 0; d < HDIM; ++d) s += qreg[d] * Kt[jj][d];
        sc[i] = s;
        mx = fmaxf(mx, s);
    }
    mx = fmaxf(mx, __shfl_xor(mx, 1));
    mx = fmaxf(mx, __shfl_xor(mx, 2));

    float sum = 0.f;
    #pragma unroll
    for (int i = 0; i < 16; ++i) {
        float e = __expf(sc[i] - mx);
        S[q][p * 16 + i] = e;
        sum += e;
    }
    sum += __shfl_xor(sum, 1);
    sum += __shfl_xor(sum, 2);
    const float inv = 1.f / sum;
    __syncthreads();

    float acc[8] = {};
    for (int jj = 0; jj < SEQL; ++jj) {
        float pv = S[q][jj];
        #pragma unroll
        for (int d = 0; d < 8; ++d) acc[d] += pv * Vt[jj][p * 8 + d];
    }
    float* orow = o + (long)(b * SEQL + q) * DMODEL + h * HDIM + p * 8;
    float4 o0, o1;
    o0.x = acc[0] * inv; o0.y = acc[1] * inv; o0.z = acc[2] * inv; o0.w = acc[3] * inv;
    o1.x = acc[4] * inv; o1.y = acc[5] * inv; o1.z = acc[6] * inv; o1.w = acc[7] * inv;
    *(float4*)orow = o0;
    *(float4*)(orow + 4) = o1;
}

__global__ __launch_bounds__(256) void add_ln_kernel(
    const float* __restrict__ xin,
    const float* __restrict__ f,
    const float* __restrict__ g,
    const float* __restrict__ bta,
    float* __restrict__ xout)
{
    const int w = threadIdx.x >> 6;
    const int lane = threadIdx.x & 63;
    const int t = blockIdx.x * 4 + w;

    float4 xv = *(const float4*)&xin[(long)t * DMODEL + lane * 4];
    float4 fv = *(const float4*)&f[(long)t * DMODEL + lane * 4];
    float v0 = xv.x + fv.x, v1 = xv.y + fv.y, v2 = xv.z + fv.z, v3 = xv.w + fv.w;

    float s  = v0 + v1 + v2 + v3;
    float sq = v0 * v0 + v1 * v1 + v2 * v2 + v3 * v3;
    #pragma unroll
    for (int off = 1; off < 64; off <<= 1) {
        s  += __shfl_xor(s, off);
        sq += __shfl_xor(sq, off);
    }
    float mean = s * (1.f / 256.f);
    float var  = sq * (1.f / 256.f) - mean * mean;
    float rs   = rsqrtf(var + 1e-5f);

    float4 gv = *(const float4*)&g[lane * 4];
    float4 bv = *(const float4*)&bta[lane * 4];
    float4 o;
    o.x = (v0 - mean) * rs * gv.x + bv.x;
    o.y = (v1 - mean) * rs * gv.y + bv.y;
    o.z = (v2 - mean) * rs * gv.z + bv.z;
    o.w = (v3 - mean) * rs * gv.w + bv.w;
    *(float4*)&xout[(long)t * DMODEL + lane * 4] = o;
}

// ---------------------------------------------------------------------------
extern "C" void kernel_launch(void* const* d_in, const int* in_sizes, int n_in,
                              void* d_out, int out_size, void* d_ws, size_t ws_size,
                              hipStream_t stream) {
    const int*   word_idx  = (const int*)d_in[0];
    const int*   ngram_idx = (const int*)d_in[1];
    const float* fc1_w = (const float*)d_in[2];
    const float* fc1_b = (const float*)d_in[3];
    const float* fc2_w = (const float*)d_in[4];
    const float* fc2_b = (const float*)d_in[5];
    const float* qkv_w = (const float*)d_in[6];
    const float* qkv_b = (const float*)d_in[7];
    const float* out_w = (const float*)d_in[8];
    const float* out_b = (const float*)d_in[9];
    const float* ln1_g = (const float*)d_in[10];
    const float* ln1_b = (const float*)d_in[11];
    const float* ff1_w = (const float*)d_in[12];
    const float* ff1_b = (const float*)d_in[13];
    const float* ff2_w = (const float*)d_in[14];
    const float* ff2_b = (const float*)d_in[15];
    const float* ln2_g = (const float*)d_in[16];
    const float* ln2_b = (const float*)d_in[17];

    float* x = (float*)d_out;  // [2048][256]

    const size_t BM_OFF   = 0;
    const size_t FC1T_OFF = 10240;
    const size_t FC1T_BYTES = (size_t)F_TOT * FFDIM * 2;
    const size_t QKVT_OFF = FC1T_OFF + FC1T_BYTES;
    const size_t QKVT_BYTES = (size_t)2 * 768 * 256 * 2;
    const size_t OUTT_OFF = QKVT_OFF + QKVT_BYTES;
    const size_t OUTT_BYTES = (size_t)2 * 256 * 256 * 2;
    const size_t FF1T_OFF = OUTT_OFF + OUTT_BYTES;
    const size_t FF1T_BYTES = (size_t)2 * 1024 * 256 * 2;
    const size_t FF2T_OFF = FF1T_OFF + FF1T_BYTES;
    const size_t FF2T_BYTES = (size_t)2 * 256 * 1024 * 2;
    const size_t ATTN_OFF = FF2T_OFF + FF2T_BYTES;
    const size_t ATTN_BYTES = (size_t)NTOK * DMODEL * 4;
    const size_t BAR_OFF  = ATTN_OFF + ATTN_BYTES;
    const size_t FAST_BYTES = BAR_OFF + 128;

    if (ws_size >= FAST_BYTES) {
        unsigned int*   bm   = (unsigned int*)((char*)d_ws + BM_OFF);
        unsigned short* fc1T = (unsigned short*)((char*)d_ws + FC1T_OFF);
        unsigned short* qkvT = (unsigned short*)((char*)d_ws + QKVT_OFF);
        unsigned short* outT = (unsigned short*)((char*)d_ws + OUTT_OFF);
        unsigned short* ff1T = (unsigned short*)((char*)d_ws + FF1T_OFF);
        unsigned short* ff2T = (unsigned short*)((char*)d_ws + FF2T_OFF);
        float* attn_raw = (float*)((char*)d_ws + ATTN_OFF);
        unsigned* bar   = (unsigned*)((char*)d_ws + BAR_OFF);

        hipMemsetAsync((void*)bar, 0, 128, stream);
        mark_feats<<<1, 256, 0, stream>>>(word_idx, ngram_idx, bm);
        transpose_cvt<<<10192, 256, 0, stream>>>(
            fc1_w, fc1T, bm, qkv_w, out_w, ff1_w, ff2_w, qkvT, outT, ff1T, ff2T);
        mega_kernel<<<NBLK, 512, 0, stream>>>(
            word_idx, ngram_idx, fc1T, fc1_b, fc2_w, fc2_b,
            qkvT, qkv_b, outT, out_b, ln1_g, ln1_b,
            ff1T, ff1_b, ff2T, ff2_b, ln2_g, ln2_b,
            x, attn_raw, bar);
    } else {
        float* wsf      = (float*)d_ws;
        float* qkvbuf   = wsf;
        float* attn_raw = qkvbuf + 2048 * 768;
        float* obuf     = attn_raw + 2048 * 256;
        float* ffbuf    = obuf + 2048 * 256;

        embed_kernel<<<NTOK / 8, 256, 0, stream>>>(word_idx, ngram_idx, fc1_w,
                                                   fc1_b, fc2_w, fc2_b, x);
        for (int i = 0; i < 2; ++i) {
            gemm_bias<false><<<dim3(768 / 64, NTOK / 64), 256, 0, stream>>>(
                x, qkv_w + (long)i * 768 * 256, qkv_b + i * 768, qkvbuf,
                NTOK, 768, 256);
            attn_kernel<<<32 * NHEAD, 256, 0, stream>>>(qkvbuf, attn_raw);
            gemm_bias<false><<<dim3(256 / 64, NTOK / 64), 256, 0, stream>>>(
                attn_raw, out_w + (long)i * 256 * 256, out_b + i * 256, obuf,
                NTOK, 256, 256);
            add_ln_kernel<<<NTOK / 4, 256, 0, stream>>>(x, obuf, ln1_g + i * 256,
                                                        ln1_b + i * 256, x);
            gemm_bias<true><<<dim3(1024 / 64, NTOK / 64), 256, 0, stream>>>(
                x, ff1_w + (long)i * 1024 * 256, ff1_b + i * 1024, ffbuf,
                NTOK, 1024, 256);
            gemm_bias<false><<<dim3(256 / 64, NTOK / 64), 256, 0, stream>>>(
                ffbuf, ff2_w + (long)i * 256 * 1024, ff2_b + i * 256, obuf,
                NTOK, 256, 1024);
            add_ln_kernel<<<NTOK / 4, 256, 0, stream>>>(x, obuf, ln2_g + i * 256,
                                                        ln2_b + i * 256, x);
        }
    }
}

// Round 9
// 153.773 us; speedup vs baseline: 2.7743x; 2.7743x over previous
//
#include <hip/hip_runtime.h>
#include <hip/hip_bf16.h>
#include <math.h>

#define WORDC 30000
#define F_TOT 80000
#define NTOK  2048
#define DMODEL 256
#define FFDIM 512
#define NHEAD 8
#define HDIM  32
#define SEQL  64

typedef __attribute__((ext_vector_type(8))) short bf16x8;
typedef __attribute__((ext_vector_type(8))) unsigned short u16x8;
typedef __attribute__((ext_vector_type(4))) float f32x4;

__device__ __forceinline__ unsigned short f32_to_bf16_rne(float x) {
    unsigned int u = __float_as_uint(x);
    unsigned int r = (u + 0x7FFFu + ((u >> 16) & 1u)) >> 16;
    return (unsigned short)r;
}

__device__ __forceinline__ u16x8 cvt8(float4 a, float4 b) {
    u16x8 v;
    v[0] = f32_to_bf16_rne(a.x); v[1] = f32_to_bf16_rne(a.y);
    v[2] = f32_to_bf16_rne(a.z); v[3] = f32_to_bf16_rne(a.w);
    v[4] = f32_to_bf16_rne(b.x); v[5] = f32_to_bf16_rne(b.y);
    v[6] = f32_to_bf16_rne(b.z); v[7] = f32_to_bf16_rne(b.w);
    return v;
}

// ---------------------------------------------------------------------------
// Build bitmap of used features (word + ngram), one block.
// ---------------------------------------------------------------------------
__global__ __launch_bounds__(256) void mark_feats(
    const int* __restrict__ word_idx,
    const int* __restrict__ ngram_idx,
    unsigned int* __restrict__ bm)
{
    __shared__ unsigned int lbm[2500];
    const int tid = threadIdx.x;
    for (int i = tid; i < 2500; i += 256) lbm[i] = 0u;
    __syncthreads();
    for (int j = tid; j < NTOK; j += 256) {
        int f = word_idx[j];
        atomicOr(&lbm[f >> 5], 1u << (f & 31));
    }
    for (int j = tid; j < NTOK * 6; j += 256) {
        int f = WORDC + ngram_idx[j];
        atomicOr(&lbm[f >> 5], 1u << (f & 31));
    }
    __syncthreads();
    for (int i = tid; i < 2500; i += 256) bm[i] = lbm[i];
}

// ---------------------------------------------------------------------------
// Transpose fc1_w (store-pruned by bitmap) + cvt transformer weights.
// ---------------------------------------------------------------------------
__global__ __launch_bounds__(256) void transpose_cvt(
    const float* __restrict__ fc1_w,
    unsigned short* __restrict__ fc1T,
    const unsigned int* __restrict__ bm,
    const float* __restrict__ s0, const float* __restrict__ s1,
    const float* __restrict__ s2, const float* __restrict__ s3,
    unsigned short* __restrict__ d0, unsigned short* __restrict__ d1,
    unsigned short* __restrict__ d2, unsigned short* __restrict__ d3)
{
    __shared__ float tile[64][65];
    const int bid = blockIdx.x;
    const int tid = threadIdx.x;

    if (bid < 10000) {
        const int f0 = (bid % 1250) * 64;
        const int j0 = (bid / 1250) * 64;

        const int fr = (tid & 15) * 4;
        const int jr = tid >> 4;
        #pragma unroll
        for (int p = 0; p < 4; ++p) {
            int j = j0 + p * 16 + jr;
            float4 v = *(const float4*)&fc1_w[(long)j * F_TOT + f0 + fr];
            tile[fr + 0][p * 16 + jr] = v.x;
            tile[fr + 1][p * 16 + jr] = v.y;
            tile[fr + 2][p * 16 + jr] = v.z;
            tile[fr + 3][p * 16 + jr] = v.w;
        }
        __syncthreads();

        const int jc  = (tid & 15) * 4;
        const int fr2 = tid >> 4;
        #pragma unroll
        for (int p = 0; p < 4; ++p) {
            int fi = p * 16 + fr2;
            int f  = f0 + fi;
            if ((bm[f >> 5] >> (f & 31)) & 1u) {
                ushort4 o;
                o.x = f32_to_bf16_rne(tile[fi][jc + 0]);
                o.y = f32_to_bf16_rne(tile[fi][jc + 1]);
                o.z = f32_to_bf16_rne(tile[fi][jc + 2]);
                o.w = f32_to_bf16_rne(tile[fi][jc + 3]);
                *(ushort4*)&fc1T[(long)f * FFDIM + j0 + jc] = o;
            }
        }
    } else {
        int s = bid - 10000;
        int ten = s / 48, b48 = s % 48;
        const float* src; unsigned short* dst; int n4;
        switch (ten) {
            case 0:  src = s0; dst = d0; n4 = 2 * 768 * 256 / 4;  break;
            case 1:  src = s1; dst = d1; n4 = 2 * 256 * 256 / 4;  break;
            case 2:  src = s2; dst = d2; n4 = 2 * 1024 * 256 / 4; break;
            default: src = s3; dst = d3; n4 = 2 * 256 * 1024 / 4; break;
        }
        for (int i = b48 * 256 + tid; i < n4; i += 48 * 256) {
            float4 v = ((const float4*)src)[i];
            ushort4 o;
            o.x = f32_to_bf16_rne(v.x);
            o.y = f32_to_bf16_rne(v.y);
            o.z = f32_to_bf16_rne(v.z);
            o.w = f32_to_bf16_rne(v.w);
            ((ushort4*)dst)[i] = o;
        }
    }
}

// ---------------------------------------------------------------------------
// Gather path: dedupe -> sum bf16 rows of fc1T -> relu -> fc2
// ---------------------------------------------------------------------------
__global__ __launch_bounds__(256) void embed_gather(
    const int* __restrict__ word_idx,
    const int* __restrict__ ngram_idx,
    const unsigned short* __restrict__ fc1_wT,
    const float* __restrict__ fc1_b,
    const float* __restrict__ fc2_w,
    const float* __restrict__ fc2_b,
    float* __restrict__ x)
{
    __shared__ int   feats[8][8];
    __shared__ int   nf[8];
    __shared__ float x1[8][FFDIM];

    const int t0  = blockIdx.x * 8;
    const int tid = threadIdx.x;

    if (tid < 8) {
        int t = t0 + tid;
        int cnt = 0;
        feats[tid][cnt++] = word_idx[t];
        for (int k = 0; k < 6; ++k) {
            int f = WORDC + ngram_idx[t * 6 + k];
            bool dup = false;
            for (int s = 1; s < cnt; ++s)
                if (feats[tid][s] == f) dup = true;
            if (!dup) feats[tid][cnt++] = f;
        }
        nf[tid] = cnt;
    }
    __syncthreads();

    const float2 bb = *(const float2*)&fc1_b[tid * 2];
    #pragma unroll
    for (int tt = 0; tt < 8; ++tt) {
        float a0 = bb.x, a1 = bb.y;
        int n = nf[tt];
        for (int s = 0; s < n; ++s) {
            unsigned int wrd = *(const unsigned int*)
                &fc1_wT[(long)feats[tt][s] * FFDIM + tid * 2];
            a0 += __uint_as_float((wrd & 0xFFFFu) << 16);
            a1 += __uint_as_float(wrd & 0xFFFF0000u);
        }
        x1[tt][tid * 2 + 0] = fmaxf(a0, 0.f);
        x1[tt][tid * 2 + 1] = fmaxf(a1, 0.f);
    }
    __syncthreads();

    const int d = tid;
    float acc[8];
    float cb = fc2_b[d];
    #pragma unroll
    for (int tt = 0; tt < 8; ++tt) acc[tt] = cb;
    const float* wrow = fc2_w + d * FFDIM;
    for (int k = 0; k < FFDIM; ++k) {
        float wv = wrow[k];
        #pragma unroll
        for (int tt = 0; tt < 8; ++tt) acc[tt] += wv * x1[tt][k];
    }
    #pragma unroll
    for (int tt = 0; tt < 8; ++tt)
        x[(t0 + tt) * DMODEL + d] = acc[tt];
}

// ---------------------------------------------------------------------------
// Fused per-(b,h) QKV GEMM + MFMA attention. 512 threads / 8 waves.
// (unchanged from R7 — proven)
// ---------------------------------------------------------------------------
__global__ __launch_bounds__(512) void fused_qkv_attn(
    const float* __restrict__ x,
    const unsigned short* __restrict__ Wq,  // layer qkvT [768][256]
    const float* __restrict__ bq,
    float* __restrict__ o)
{
    __shared__ unsigned short sA[64 * 264];
    __shared__ unsigned short sWp[8][48 * 72];
    __shared__ unsigned short sQ[64 * 40];
    __shared__ unsigned short sK[64 * 40];
    __shared__ unsigned short sVt[32 * 72];
    __shared__ unsigned short sP[64 * 72];
    __shared__ float sfmx[2][64];
    __shared__ float sfsm[2][64];

    const int b = blockIdx.x >> 3;
    const int h = blockIdx.x & 7;
    const int tid  = threadIdx.x;
    const int lane = tid & 63;
    const int w    = tid >> 6;          // 0..7
    const int rg   = w & 3;             // query-row group
    const int ch   = w >> 2;            // col half
    const int fr   = lane & 15;
    const int ksub = lane >> 4;
    const int row0 = b * SEQL;

    #pragma unroll
    for (int j = 0; j < 4; ++j) {
        int c = j * 512 + tid;
        int row = c >> 5, c8 = c & 31;
        const float* ap = &x[(long)(row0 + row) * DMODEL + c8 * 8];
        float4 a0 = *(const float4*)ap;
        float4 a1 = *(const float4*)(ap + 4);
        *(u16x8*)&sA[row * 264 + c8 * 8] = cvt8(a0, a1);
    }

    int lr6[6], grow6[6];
    const int wcc = (lane & 7) * 8;
    #pragma unroll
    for (int j = 0; j < 6; ++j) {
        int lr = j * 8 + (lane >> 3);
        lr6[j] = lr;
        int c = ch * 48 + lr;
        grow6[j] = (c >> 5) * 256 + h * HDIM + (c & 31);
    }
    u16x8 wc[6], wn[6];
    #pragma unroll
    for (int j = 0; j < 6; ++j)
        wc[j] = *(const u16x8*)&Wq[(long)grow6[j] * DMODEL + wcc];

    __syncthreads();   // sA ready

    f32x4 acc[3] = {};
    for (int t = 0; t < 4; ++t) {
        #pragma unroll
        for (int j = 0; j < 6; ++j)
            *(u16x8*)&sWp[w][lr6[j] * 72 + wcc] = wc[j];
        if (t < 3) {
            int k0 = (t + 1) * 64;
            #pragma unroll
            for (int j = 0; j < 6; ++j)
                wn[j] = *(const u16x8*)&Wq[(long)grow6[j] * DMODEL + k0 + wcc];
        }
        #pragma unroll
        for (int kk = 0; kk < 2; ++kk) {
            bf16x8 af = *(bf16x8*)&sA[(rg * 16 + fr) * 264 + t * 64 + kk * 32 + ksub * 8];
            #pragma unroll
            for (int ni = 0; ni < 3; ++ni) {
                bf16x8 bf = *(bf16x8*)&sWp[w][(ni * 16 + fr) * 72 + kk * 32 + ksub * 8];
                acc[ni] = __builtin_amdgcn_mfma_f32_16x16x32_bf16(af, bf, acc[ni], 0, 0, 0);
            }
        }
        if (t < 3) {
            #pragma unroll
            for (int j = 0; j < 6; ++j) wc[j] = wn[j];
        }
    }

    const float scale = 0.17677669529663687f;   // 1/sqrt(32)
    #pragma unroll
    for (int ni = 0; ni < 3; ++ni) {
        int c = ch * 48 + ni * 16 + fr;
        int part = c >> 5, pc = c & 31;
        float bv = bq[part * 256 + h * HDIM + pc];
        #pragma unroll
        for (int r = 0; r < 4; ++r) {
            int row = rg * 16 + ksub * 4 + r;
            float v = acc[ni][r] + bv;
            if (part == 0)      sQ[row * 40 + pc] = f32_to_bf16_rne(v * scale);
            else if (part == 1) sK[row * 40 + pc] = f32_to_bf16_rne(v);
            else                sVt[pc * 72 + row] = f32_to_bf16_rne(v);
        }
    }
    __syncthreads();

    f32x4 s4[2];
    {
        bf16x8 afq = *(bf16x8*)&sQ[(rg * 16 + fr) * 40 + ksub * 8];
        #pragma unroll
        for (int ni = 0; ni < 2; ++ni) {
            bf16x8 bfk = *(bf16x8*)&sK[(ch * 32 + ni * 16 + fr) * 40 + ksub * 8];
            f32x4 z = {};
            s4[ni] = __builtin_amdgcn_mfma_f32_16x16x32_bf16(afq, bfk, z, 0, 0, 0);
        }
    }

    #pragma unroll
    for (int r = 0; r < 4; ++r) {
        float m = fmaxf(s4[0][r], s4[1][r]);
        m = fmaxf(m, __shfl_xor(m, 1));
        m = fmaxf(m, __shfl_xor(m, 2));
        m = fmaxf(m, __shfl_xor(m, 4));
        m = fmaxf(m, __shfl_xor(m, 8));
        if (fr == 0) sfmx[ch][rg * 16 + ksub * 4 + r] = m;
    }
    __syncthreads();
    float minv[4];
    #pragma unroll
    for (int r = 0; r < 4; ++r) {
        int row = rg * 16 + ksub * 4 + r;
        float m = fmaxf(sfmx[0][row], sfmx[1][row]);
        float p0 = __expf(s4[0][r] - m);
        float p1 = __expf(s4[1][r] - m);
        sP[row * 72 + ch * 32 + fr]      = f32_to_bf16_rne(p0);
        sP[row * 72 + ch * 32 + 16 + fr] = f32_to_bf16_rne(p1);
        float s = p0 + p1;
        s += __shfl_xor(s, 1);
        s += __shfl_xor(s, 2);
        s += __shfl_xor(s, 4);
        s += __shfl_xor(s, 8);
        if (fr == 0) sfsm[ch][row] = s;
    }
    __syncthreads();
    #pragma unroll
    for (int r = 0; r < 4; ++r) {
        int row = rg * 16 + ksub * 4 + r;
        minv[r] = 1.f / (sfsm[0][row] + sfsm[1][row]);
    }

    f32x4 o4 = {};
    #pragma unroll
    for (int kc = 0; kc < 2; ++kc) {
        bf16x8 afp = *(bf16x8*)&sP[(rg * 16 + fr) * 72 + kc * 32 + ksub * 8];
        bf16x8 bfv = *(bf16x8*)&sVt[(ch * 16 + fr) * 72 + kc * 32 + ksub * 8];
        o4 = __builtin_amdgcn_mfma_f32_16x16x32_bf16(afp, bfv, o4, 0, 0, 0);
    }
    #pragma unroll
    for (int r = 0; r < 4; ++r) {
        int row = row0 + rg * 16 + ksub * 4 + r;
        o[(long)row * DMODEL + h * HDIM + ch * 16 + fr] = o4[r] * minv[r];
    }
}

// ---------------------------------------------------------------------------
// Fused out-proj + LN1 + FFN + LN2 for 8 rows. grid 256, 512 thr / 8 waves.
// LN1 output lives only in LDS (bf16 A-operand + f32 residual).
// ---------------------------------------------------------------------------
__global__ __launch_bounds__(512) void outln_ffn(
    const float* __restrict__ attn_raw,
    const unsigned short* __restrict__ Wo,   // [256][256] bf16
    const float* __restrict__ bo,
    const float* __restrict__ g1, const float* __restrict__ b1t,
    const unsigned short* __restrict__ W1,   // [1024][256] bf16
    const float* __restrict__ b1,
    const unsigned short* __restrict__ W2,   // [256][1024] bf16
    const float* __restrict__ b2,
    const float* __restrict__ g2, const float* __restrict__ b2t,
    float* __restrict__ x)                   // residual in, final out
{
    __shared__ unsigned short sA[16 * 264];   // bf16 A (attn_raw, then xn)
    __shared__ float xnf[8 * 264];            // LN1 out f32 (residual for LN2)
    __shared__ unsigned short x1s[16 * 1032];
    __shared__ unsigned short sWp[8][32 * 72];
    __shared__ float redS[8][8];
    __shared__ float redQ[8][8];

    const int tid  = threadIdx.x;
    const int lane = tid & 63;
    const int w    = tid >> 6;
    const int fr   = lane & 15;
    const int ksub = lane >> 4;
    const int m0   = blockIdx.x * 8;

    const int lrb = lane >> 3;
    const int wcc = (lane & 7) * 8;

    // ---- stage attn_raw rows 0..7 (bf16), zero rows 8..15 ----
    {
        int row = tid >> 5, c8 = tid & 31;
        if (tid < 256) {
            const float* ap = &attn_raw[(long)(m0 + row) * DMODEL + c8 * 8];
            float4 a0 = *(const float4*)ap;
            float4 a1 = *(const float4*)(ap + 4);
            *(u16x8*)&sA[row * 264 + c8 * 8] = cvt8(a0, a1);
        } else {
            u16x8 z = {};
            *(u16x8*)&sA[row * 264 + c8 * 8] = z;
        }
    }

    u16x8 wc[4], wn[4];
    #pragma unroll
    for (int j = 0; j < 4; ++j)
        wc[j] = *(const u16x8*)&Wo[(long)(w * 32 + j * 8 + lrb) * DMODEL + wcc];

    __syncthreads();

    // ---- phase A: out-projection, barrier-free k-loop ----
    f32x4 acc[2] = {};
    for (int t = 0; t < 4; ++t) {
        #pragma unroll
        for (int j = 0; j < 4; ++j)
            *(u16x8*)&sWp[w][(j * 8 + lrb) * 72 + wcc] = wc[j];
        if (t < 3) {
            int k0 = (t + 1) * 64;
            #pragma unroll
            for (int j = 0; j < 4; ++j)
                wn[j] = *(const u16x8*)&Wo[(long)(w * 32 + j * 8 + lrb) * DMODEL + k0 + wcc];
        }
        #pragma unroll
        for (int kk = 0; kk < 2; ++kk) {
            bf16x8 af = *(bf16x8*)&sA[fr * 264 + t * 64 + kk * 32 + ksub * 8];
            #pragma unroll
            for (int ni = 0; ni < 2; ++ni) {
                bf16x8 bf = *(bf16x8*)&sWp[w][(ni * 16 + fr) * 72 + kk * 32 + ksub * 8];
                acc[ni] = __builtin_amdgcn_mfma_f32_16x16x32_bf16(af, bf, acc[ni], 0, 0, 0);
            }
        }
        if (t < 3) {
            #pragma unroll
            for (int j = 0; j < 4; ++j) wc[j] = wn[j];
        }
    }

    // vres = acc + bo + residual(x)
    float vres[2][4];
    #pragma unroll
    for (int ni = 0; ni < 2; ++ni) {
        int col = w * 32 + ni * 16 + fr;
        float bv = bo[col];
        #pragma unroll
        for (int r = 0; r < 4; ++r) {
            int rl = ksub * 4 + r;
            vres[ni][r] = (rl < 8)
                ? acc[ni][r] + bv + x[(long)(m0 + rl) * DMODEL + col]
                : 0.f;
        }
    }

    #pragma unroll
    for (int r = 0; r < 4; ++r) {
        float s  = vres[0][r] + vres[1][r];
        float qq = vres[0][r] * vres[0][r] + vres[1][r] * vres[1][r];
        #pragma unroll
        for (int mask = 1; mask < 16; mask <<= 1) {
            s  += __shfl_xor(s, mask);
            qq += __shfl_xor(qq, mask);
        }
        if (fr == 0 && ksub < 2) {
            redS[w][ksub * 4 + r] = s;
            redQ[w][ksub * 4 + r] = qq;
        }
    }
    // prefetch first W1 chunk while waiting
    #pragma unroll
    for (int j = 0; j < 4; ++j)
        wc[j] = *(const u16x8*)&W1[(long)(w * 32 + j * 8 + lrb) * DMODEL + wcc];

    __syncthreads();   // sA reads done + redS ready

    // LN1 -> write xn into sA(bf16 rows 0..7) and xnf(f32)
    #pragma unroll
    for (int r = 0; r < 4; ++r) {
        int rl = ksub * 4 + r;
        if (rl < 8) {
            float sum = 0.f, sumq = 0.f;
            #pragma unroll
            for (int ww = 0; ww < 8; ++ww) {
                sum  += redS[ww][rl];
                sumq += redQ[ww][rl];
            }
            float mean = sum * (1.f / 256.f);
            float var  = sumq * (1.f / 256.f) - mean * mean;
            float rstd = rsqrtf(var + 1e-5f);
            #pragma unroll
            for (int ni = 0; ni < 2; ++ni) {
                int col = w * 32 + ni * 16 + fr;
                float v = (vres[ni][r] - mean) * rstd * g1[col] + b1t[col];
                xnf[rl * 264 + col] = v;
                sA[rl * 264 + col] = f32_to_bf16_rne(v);
            }
        }
    }
    __syncthreads();   // xn ready for all waves

    // ---- phase B: FFN (ff1 t=0..15, ff2 t=16..31), wave-private W ----
    f32x4 acc2[2] = {};
    for (int t = 0; t < 32; ++t) {
        #pragma unroll
        for (int j = 0; j < 4; ++j)
            *(u16x8*)&sWp[w][(j * 8 + lrb) * 72 + wcc] = wc[j];
        if (t < 31) {
            int tn = t + 1;
            if (tn < 16) {
                int nc = tn >> 2, kq = tn & 3;
                #pragma unroll
                for (int j = 0; j < 4; ++j)
                    wn[j] = *(const u16x8*)&W1[(long)(nc * 256 + w * 32 + j * 8 + lrb) * DMODEL
                                               + kq * 64 + wcc];
            } else {
                int t2 = tn - 16;
                #pragma unroll
                for (int j = 0; j < 4; ++j)
                    wn[j] = *(const u16x8*)&W2[(long)(w * 32 + j * 8 + lrb) * 1024
                                               + t2 * 64 + wcc];
            }
        }
        #pragma unroll
        for (int kk = 0; kk < 2; ++kk) {
            bf16x8 af;
            if (t < 16)
                af = *(bf16x8*)&sA[fr * 264 + (t & 3) * 64 + kk * 32 + ksub * 8];
            else
                af = *(bf16x8*)&x1s[fr * 1032 + (t - 16) * 64 + kk * 32 + ksub * 8];
            #pragma unroll
            for (int ni = 0; ni < 2; ++ni) {
                bf16x8 bf = *(bf16x8*)&sWp[w][(ni * 16 + fr) * 72 + kk * 32 + ksub * 8];
                acc2[ni] = __builtin_amdgcn_mfma_f32_16x16x32_bf16(af, bf, acc2[ni], 0, 0, 0);
            }
        }
        if (t < 16 && (t & 3) == 3) {
            int nc = t >> 2;
            #pragma unroll
            for (int ni = 0; ni < 2; ++ni) {
                int col = nc * 256 + w * 32 + ni * 16 + fr;
                float bv = b1[col];
                #pragma unroll
                for (int r = 0; r < 4; ++r) {
                    int rl = ksub * 4 + r;
                    x1s[rl * 1032 + col] = (rl < 8)
                        ? f32_to_bf16_rne(fmaxf(acc2[ni][r] + bv, 0.f))
                        : (unsigned short)0;
                }
                acc2[ni] = (f32x4){};
            }
        }
        if (t == 15) __syncthreads();    // x1s complete before ff2 reads
        if (t < 31) {
            #pragma unroll
            for (int j = 0; j < 4; ++j) wc[j] = wn[j];
        }
    }

    // ---- epilogue: + b2 + residual(xnf), LN2, write x ----
    float vres2[2][4];
    #pragma unroll
    for (int ni = 0; ni < 2; ++ni) {
        int col = w * 32 + ni * 16 + fr;
        float bv = b2[col];
        #pragma unroll
        for (int r = 0; r < 4; ++r) {
            int rl = ksub * 4 + r;
            vres2[ni][r] = (rl < 8)
                ? acc2[ni][r] + bv + xnf[rl * 264 + col]
                : 0.f;
        }
    }

    #pragma unroll
    for (int r = 0; r < 4; ++r) {
        float s  = vres2[0][r] + vres2[1][r];
        float qq = vres2[0][r] * vres2[0][r] + vres2[1][r] * vres2[1][r];
        #pragma unroll
        for (int mask = 1; mask < 16; mask <<= 1) {
            s  += __shfl_xor(s, mask);
            qq += __shfl_xor(qq, mask);
        }
        if (fr == 0 && ksub < 2) {
            redS[w][ksub * 4 + r] = s;
            redQ[w][ksub * 4 + r] = qq;
        }
    }
    __syncthreads();

    #pragma unroll
    for (int r = 0; r < 4; ++r) {
        int rl = ksub * 4 + r;
        if (rl < 8) {
            float sum = 0.f, sumq = 0.f;
            #pragma unroll
            for (int ww = 0; ww < 8; ++ww) {
                sum  += redS[ww][rl];
                sumq += redQ[ww][rl];
            }
            float mean = sum * (1.f / 256.f);
            float var  = sumq * (1.f / 256.f) - mean * mean;
            float rstd = rsqrtf(var + 1e-5f);
            #pragma unroll
            for (int ni = 0; ni < 2; ++ni) {
                int col = w * 32 + ni * 16 + fr;
                x[(long)(m0 + rl) * DMODEL + col] =
                    (vres2[ni][r] - mean) * rstd * g2[col] + b2t[col];
            }
        }
    }
}

// ===========================================================================
// Fallback (fp32) path kernels — used only if ws is too small.
// ===========================================================================
__global__ __launch_bounds__(256) void embed_kernel(
    const int* __restrict__ word_idx,
    const int* __restrict__ ngram_idx,
    const float* __restrict__ fc1_w,
    const float* __restrict__ fc1_b,
    const float* __restrict__ fc2_w,
    const float* __restrict__ fc2_b,
    float* __restrict__ x)
{
    __shared__ int   feats[8][8];
    __shared__ int   nf[8];
    __shared__ float x1[8][FFDIM];

    const int t0  = blockIdx.x * 8;
    const int tid = threadIdx.x;

    if (tid < 8) {
        int t = t0 + tid;
        int cnt = 0;
        feats[tid][cnt++] = word_idx[t];
        for (int k = 0; k < 6; ++k) {
            int f = WORDC + ngram_idx[t * 6 + k];
            bool dup = false;
            for (int s = 1; s < cnt; ++s)
                if (feats[tid][s] == f) dup = true;
            if (!dup) feats[tid][cnt++] = f;
        }
        nf[tid] = cnt;
    }
    __syncthreads();

    for (int it = 0; it < 16; ++it) {
        int item = it * 256 + tid;
        int tt = item >> 9;
        int j  = item & 511;
        float acc = fc1_b[j];
        int n = nf[tt];
        const float* rowbase = fc1_w + (long)j * F_TOT;
        for (int s = 0; s < n; ++s)
            acc += rowbase[feats[tt][s]];
        x1[tt][j] = fmaxf(acc, 0.f);
    }
    __syncthreads();

    const int d = tid;
    float acc[8];
    float bb = fc2_b[d];
    #pragma unroll
    for (int tt = 0; tt < 8; ++tt) acc[tt] = bb;
    const float* wrow = fc2_w + d * FFDIM;
    for (int k = 0; k < FFDIM; ++k) {
        float wv = wrow[k];
        #pragma unroll
        for (int tt = 0; tt < 8; ++tt) acc[tt] += wv * x1[tt][k];
    }
    #pragma unroll
    for (int tt = 0; tt < 8; ++tt)
        x[(t0 + tt) * DMODEL + d] = acc[tt];
}

template<bool RELU>
__global__ __launch_bounds__(256) void gemm_bias(
    const float* __restrict__ A,
    const float* __restrict__ W,
    const float* __restrict__ bias,
    float* __restrict__ C,
    int M, int N, int K)
{
    __shared__ float sA[16][64];
    __shared__ float sW[16][64];

    const int tid = threadIdx.x;
    const int tx = tid & 15;
    const int ty = tid >> 4;
    const int m0 = blockIdx.y * 64;
    const int n0 = blockIdx.x * 64;

    const int lr = tid >> 2;
    const int lc = tid & 3;

    float acc[4][4] = {};

    for (int k0 = 0; k0 < K; k0 += 16) {
        float4 av = *(const float4*)&A[(long)(m0 + lr) * K + k0 + lc * 4];
        float4 wv = *(const float4*)&W[(long)(n0 + lr) * K + k0 + lc * 4];
        __syncthreads();
        sA[lc * 4 + 0][lr] = av.x; sA[lc * 4 + 1][lr] = av.y;
        sA[lc * 4 + 2][lr] = av.z; sA[lc * 4 + 3][lr] = av.w;
        sW[lc * 4 + 0][lr] = wv.x; sW[lc * 4 + 1][lr] = wv.y;
        sW[lc * 4 + 2][lr] = wv.z; sW[lc * 4 + 3][lr] = wv.w;
        __syncthreads();
        #pragma unroll
        for (int k = 0; k < 16; ++k) {
            float4 a4 = *(const float4*)&sA[k][ty * 4];
            float4 b4 = *(const float4*)&sW[k][tx * 4];
            float am[4] = {a4.x, a4.y, a4.z, a4.w};
            float bn[4] = {b4.x, b4.y, b4.z, b4.w};
            #pragma unroll
            for (int i = 0; i < 4; ++i)
                #pragma unroll
                for (int j = 0; j < 4; ++j)
                    acc[i][j] += am[i] * bn[j];
        }
    }

    float4 bv = *(const float4*)&bias[n0 + tx * 4];
    #pragma unroll
    for (int i = 0; i < 4; ++i) {
        int m = m0 + ty * 4 + i;
        float4 o;
        o.x = acc[i][0] + bv.x;
        o.y = acc[i][1] + bv.y;
        o.z = acc[i][2] + bv.z;
        o.w = acc[i][3] + bv.w;
        if (RELU) {
            o.x = fmaxf(o.x, 0.f); o.y = fmaxf(o.y, 0.f);
            o.z = fmaxf(o.z, 0.f); o.w = fmaxf(o.w, 0.f);
        }
        *(float4*)&C[(long)m * N + n0 + tx * 4] = o;
    }
}

__global__ __launch_bounds__(256) void attn_kernel(
    const float* __restrict__ qkv,
    float* __restrict__ o)
{
    const int b = blockIdx.x >> 3;
    const int h = blockIdx.x & 7;
    const int tid = threadIdx.x;
    const int q = tid >> 2;
    const int p = tid & 3;

    __shared__ float Kt[SEQL][HDIM + 1];
    __shared__ float Vt[SEQL][HDIM + 1];
    __shared__ float S[SEQL][SEQL + 1];

    const float scale = 0.17677669529663687f;

    {
        int fidx = tid * 2;
        int row  = fidx >> 3;
        int c    = (fidx & 7) * 4;
        const float* kb = qkv + (long)(b * SEQL + row) * 768 + 256 + h * HDIM + c;
        float4 k0 = *(const float4*)kb;
        float4 k1 = *(const float4*)(kb + 4);
        float4 v0 = *(const float4*)(kb + 256);
        float4 v1 = *(const float4*)(kb + 260);
        *(float4*)&Kt[row][c]     = k0;
        *(float4*)&Kt[row][c + 4] = k1;
        *(float4*)&Vt[row][c]     = v0;
        *(float4*)&Vt[row][c + 4] = v1;
    }

    float qreg[HDIM];
    {
        const float* qb = qkv + (long)(b * SEQL + q) * 768 + h * HDIM;
        #pragma unroll
        for (int c = 0; c < HDIM / 4; ++c) {
            float4 v = *(const float4*)(qb + c * 4);
            qreg[c * 4 + 0] = v.x * scale;
            qreg[c * 4 + 1] = v.y * scale;
            qreg[c * 4 + 2] = v.z * scale;
            qreg[c * 4 + 3] = v.w * scale;
        }
    }
    __syncthreads();

    float sc[16];
    float mx = -1e30f;
    #pragma unroll
    for (int i = 0; i < 16; ++i) {
        int jj = p * 16 + i;
        float s = 0.f;
        #pragma unroll
        for (int d = 0; d < HDIM; ++d) s += qreg[d] * Kt[jj][d];
        sc[i] = s;
        mx = fmaxf(mx, s);
    }
    mx = fmaxf(mx, __shfl_xor(mx, 1));
    mx = fmaxf(mx, __shfl_xor(mx, 2));

    float sum = 0.f;
    #pragma unroll
    for (int i = 0; i < 16; ++i) {
        float e = __expf(sc[i] - mx);
        S[q][p * 16 + i] = e;
        sum += e;
    }
    sum += __shfl_xor(sum, 1);
    sum += __shfl_xor(sum, 2);
    const float inv = 1.f / sum;
    __syncthreads();

    float acc[8] = {};
    for (int jj = 0; jj < SEQL; ++jj) {
        float pv = S[q][jj];
        #pragma unroll
        for (int d = 0; d < 8; ++d) acc[d] += pv * Vt[jj][p * 8 + d];
    }
    float* orow = o + (long)(b * SEQL + q) * DMODEL + h * HDIM + p * 8;
    float4 o0, o1;
    o0.x = acc[0] * inv; o0.y = acc[1] * inv; o0.z = acc[2] * inv; o0.w = acc[3] * inv;
    o1.x = acc[4] * inv; o1.y = acc[5] * inv; o1.z = acc[6] * inv; o1.w = acc[7] * inv;
    *(float4*)orow = o0;
    *(float4*)(orow + 4) = o1;
}

__global__ __launch_bounds__(256) void add_ln_kernel(
    const float* __restrict__ xin,
    const float* __restrict__ f,
    const float* __restrict__ g,
    const float* __restrict__ bta,
    float* __restrict__ xout)
{
    const int w = threadIdx.x >> 6;
    const int lane = threadIdx.x & 63;
    const int t = blockIdx.x * 4 + w;

    float4 xv = *(const float4*)&xin[(long)t * DMODEL + lane * 4];
    float4 fv = *(const float4*)&f[(long)t * DMODEL + lane * 4];
    float v0 = xv.x + fv.x, v1 = xv.y + fv.y, v2 = xv.z + fv.z, v3 = xv.w + fv.w;

    float s  = v0 + v1 + v2 + v3;
    float sq = v0 * v0 + v1 * v1 + v2 * v2 + v3 * v3;
    #pragma unroll
    for (int off = 1; off < 64; off <<= 1) {
        s  += __shfl_xor(s, off);
        sq += __shfl_xor(sq, off);
    }
    float mean = s * (1.f / 256.f);
    float var  = sq * (1.f / 256.f) - mean * mean;
    float rs   = rsqrtf(var + 1e-5f);

    float4 gv = *(const float4*)&g[lane * 4];
    float4 bv = *(const float4*)&bta[lane * 4];
    float4 o;
    o.x = (v0 - mean) * rs * gv.x + bv.x;
    o.y = (v1 - mean) * rs * gv.y + bv.y;
    o.z = (v2 - mean) * rs * gv.z + bv.z;
    o.w = (v3 - mean) * rs * gv.w + bv.w;
    *(float4*)&xout[(long)t * DMODEL + lane * 4] = o;
}

// ---------------------------------------------------------------------------
extern "C" void kernel_launch(void* const* d_in, const int* in_sizes, int n_in,
                              void* d_out, int out_size, void* d_ws, size_t ws_size,
                              hipStream_t stream) {
    const int*   word_idx  = (const int*)d_in[0];
    const int*   ngram_idx = (const int*)d_in[1];
    const float* fc1_w = (const float*)d_in[2];
    const float* fc1_b = (const float*)d_in[3];
    const float* fc2_w = (const float*)d_in[4];
    const float* fc2_b = (const float*)d_in[5];
    const float* qkv_w = (const float*)d_in[6];
    const float* qkv_b = (const float*)d_in[7];
    const float* out_w = (const float*)d_in[8];
    const float* out_b = (const float*)d_in[9];
    const float* ln1_g = (const float*)d_in[10];
    const float* ln1_b = (const float*)d_in[11];
    const float* ff1_w = (const float*)d_in[12];
    const float* ff1_b = (const float*)d_in[13];
    const float* ff2_w = (const float*)d_in[14];
    const float* ff2_b = (const float*)d_in[15];
    const float* ln2_g = (const float*)d_in[16];
    const float* ln2_b = (const float*)d_in[17];

    float* x = (float*)d_out;  // [2048][256]

    const size_t BM_OFF   = 0;
    const size_t FC1T_OFF = 10240;
    const size_t FC1T_BYTES = (size_t)F_TOT * FFDIM * 2;
    const size_t QKVT_OFF = FC1T_OFF + FC1T_BYTES;
    const size_t QKVT_BYTES = (size_t)2 * 768 * 256 * 2;
    const size_t OUTT_OFF = QKVT_OFF + QKVT_BYTES;
    const size_t OUTT_BYTES = (size_t)2 * 256 * 256 * 2;
    const size_t FF1T_OFF = OUTT_OFF + OUTT_BYTES;
    const size_t FF1T_BYTES = (size_t)2 * 1024 * 256 * 2;
    const size_t FF2T_OFF = FF1T_OFF + FF1T_BYTES;
    const size_t FF2T_BYTES = (size_t)2 * 256 * 1024 * 2;
    const size_t ATTN_OFF = FF2T_OFF + FF2T_BYTES;
    const size_t ATTN_BYTES = (size_t)NTOK * DMODEL * 4;
    const size_t FAST_BYTES = ATTN_OFF + ATTN_BYTES;

    if (ws_size >= FAST_BYTES) {
        unsigned int*   bm   = (unsigned int*)((char*)d_ws + BM_OFF);
        unsigned short* fc1T = (unsigned short*)((char*)d_ws + FC1T_OFF);
        unsigned short* qkvT = (unsigned short*)((char*)d_ws + QKVT_OFF);
        unsigned short* outT = (unsigned short*)((char*)d_ws + OUTT_OFF);
        unsigned short* ff1T = (unsigned short*)((char*)d_ws + FF1T_OFF);
        unsigned short* ff2T = (unsigned short*)((char*)d_ws + FF2T_OFF);
        float* attn_raw = (float*)((char*)d_ws + ATTN_OFF);

        mark_feats<<<1, 256, 0, stream>>>(word_idx, ngram_idx, bm);
        transpose_cvt<<<10192, 256, 0, stream>>>(
            fc1_w, fc1T, bm, qkv_w, out_w, ff1_w, ff2_w, qkvT, outT, ff1T, ff2T);
        embed_gather<<<NTOK / 8, 256, 0, stream>>>(word_idx, ngram_idx, fc1T,
                                                   fc1_b, fc2_w, fc2_b, x);

        for (int i = 0; i < 2; ++i) {
            fused_qkv_attn<<<32 * NHEAD, 512, 0, stream>>>(
                x, qkvT + (long)i * 768 * 256, qkv_b + i * 768, attn_raw);

            outln_ffn<<<NTOK / 8, 512, 0, stream>>>(
                attn_raw, outT + (long)i * 256 * 256, out_b + i * 256,
                ln1_g + i * 256, ln1_b + i * 256,
                ff1T + (long)i * 1024 * 256, ff1_b + i * 1024,
                ff2T + (long)i * 256 * 1024, ff2_b + i * 256,
                ln2_g + i * 256, ln2_b + i * 256, x);
        }
    } else {
        float* wsf      = (float*)d_ws;
        float* qkvbuf   = wsf;
        float* attn_raw = qkvbuf + 2048 * 768;
        float* obuf     = attn_raw + 2048 * 256;
        float* ffbuf    = obuf + 2048 * 256;

        embed_kernel<<<NTOK / 8, 256, 0, stream>>>(word_idx, ngram_idx, fc1_w,
                                                   fc1_b, fc2_w, fc2_b, x);
        for (int i = 0; i < 2; ++i) {
            gemm_bias<false><<<dim3(768 / 64, NTOK / 64), 256, 0, stream>>>(
                x, qkv_w + (long)i * 768 * 256, qkv_b + i * 768, qkvbuf,
                NTOK, 768, 256);
            attn_kernel<<<32 * NHEAD, 256, 0, stream>>>(qkvbuf, attn_raw);
            gemm_bias<false><<<dim3(256 / 64, NTOK / 64), 256, 0, stream>>>(
                attn_raw, out_w + (long)i * 256 * 256, out_b + i * 256, obuf,
                NTOK, 256, 256);
            add_ln_kernel<<<NTOK / 4, 256, 0, stream>>>(x, obuf, ln1_g + i * 256,
                                                        ln1_b + i * 256, x);
            gemm_bias<true><<<dim3(1024 / 64, NTOK / 64), 256, 0, stream>>>(
                x, ff1_w + (long)i * 1024 * 256, ff1_b + i * 1024, ffbuf,
                NTOK, 1024, 256);
            gemm_bias<false><<<dim3(256 / 64, NTOK / 64), 256, 0, stream>>>(
                ffbuf, ff2_w + (long)i * 256 * 1024, ff2_b + i * 256, obuf,
                NTOK, 256, 1024);
            add_ln_kernel<<<NTOK / 4, 256, 0, stream>>>(x, obuf, ln2_g + i * 256,
                                                        ln2_b + i * 256, x);
        }
    }
}